// Round 1
// baseline (1109.572 us; speedup 1.0000x reference)
//
#include <hip/hip_runtime.h>

#define B_ 64
#define T_ 2048
#define I_ 128
#define H_ 128

// ---------------- Phase 1: xp = x @ W_xh^T + b_xh ----------------
// grid = (B*T)/128 blocks, 256 threads.
// Thread: row r = tid&127 (global row = blockIdx.x*128+r), col-half ch = tid>>7.
// Computes xp[row][ch*64 .. ch*64+63]; W_xh staged in LDS, read wave-uniform
// (broadcast, conflict-free). Output written into d_out's h_seq region.
__global__ __launch_bounds__(256) void xp_gemm(
    const float* __restrict__ x, const float* __restrict__ Wxh,
    const float* __restrict__ bxh, float* __restrict__ xp)
{
    __shared__ float ws[H_ * I_];   // 64 KB
    const int tid = threadIdx.x;
    {
        const float4* src = (const float4*)Wxh;
        float4* dst = (float4*)ws;
        #pragma unroll
        for (int i = 0; i < (H_ * I_ / 4) / 256; ++i)
            dst[tid + i * 256] = src[tid + i * 256];
    }
    __syncthreads();

    const int r  = tid & 127;
    const int ch = tid >> 7;
    const long row = (long)blockIdx.x * 128 + r;
    const float* xrow = x + row * I_;
    const float* wb = ws + ch * 64 * I_;

    float acc[64];
    #pragma unroll
    for (int c = 0; c < 64; ++c) acc[c] = 0.f;

    for (int k4 = 0; k4 < I_ / 4; ++k4) {
        const float4 xv = *(const float4*)(xrow + k4 * 4);
        #pragma unroll
        for (int c = 0; c < 64; ++c) {
            const float4 wv = *(const float4*)(wb + c * I_ + k4 * 4);
            acc[c] = fmaf(xv.x, wv.x, acc[c]);
            acc[c] = fmaf(xv.y, wv.y, acc[c]);
            acc[c] = fmaf(xv.z, wv.z, acc[c]);
            acc[c] = fmaf(xv.w, wv.w, acc[c]);
        }
    }

    float* orow = xp + row * H_ + ch * 64;
    const float4* bv = (const float4*)(bxh + ch * 64);
    #pragma unroll
    for (int c4 = 0; c4 < 16; ++c4) {
        const float4 b4 = bv[c4];
        float4 o;
        o.x = acc[c4 * 4 + 0] + b4.x;
        o.y = acc[c4 * 4 + 1] + b4.y;
        o.z = acc[c4 * 4 + 2] + b4.z;
        o.w = acc[c4 * 4 + 3] + b4.w;
        *(float4*)(orow + c4 * 4) = o;
    }
}

// ---------------- Phase 2: sequential scan, one block per batch ----------------
// 256 threads: lane pair (2j, 2j+1) owns output j; half = tid&1 selects K-half.
// W_hh row-half (64 floats) stationary in VGPRs. h double-buffered in LDS,
// one __syncthreads per step. xp read (and h_seq written) in-place in d_out.
__global__ __launch_bounds__(256) void rnn_scan(
    const float* __restrict__ Whh, const float* __restrict__ bhh,
    float* seq /* [B][T][H]: xp on input, h_seq on output */,
    float* hlast /* [B][H] */)
{
    __shared__ float hb[2][H_];
    const int tid  = threadIdx.x;
    const int j    = tid >> 1;
    const int half = tid & 1;
    const int b    = blockIdx.x;

    float w[64];
    {
        const float* wr = Whh + j * H_ + half * 64;
        #pragma unroll
        for (int i4 = 0; i4 < 16; ++i4) {
            const float4 v = *(const float4*)(wr + i4 * 4);
            w[i4 * 4 + 0] = v.x; w[i4 * 4 + 1] = v.y;
            w[i4 * 4 + 2] = v.z; w[i4 * 4 + 3] = v.w;
        }
    }
    const float bj = bhh[j];
    if (tid < H_) hb[0][tid] = 0.f;

    float* xp = seq + (long)b * T_ * H_;
    float xnext = xp[j];           // prefetch t=0
    __syncthreads();

    int cur = 0;
    for (int t = 0; t < T_; ++t) {
        const float xcur = xnext;
        {
            const int tn = (t + 1 < T_) ? (t + 1) : t;
            xnext = xp[(long)tn * H_ + j];   // prefetch next step (hides HBM/L2 latency)
        }
        const float* hc = hb[cur];
        float a0 = 0.f, a1 = 0.f, a2 = 0.f, a3 = 0.f;
        #pragma unroll
        for (int i4 = 0; i4 < 16; ++i4) {
            const float4 hv = *(const float4*)(hc + half * 64 + i4 * 4);
            a0 = fmaf(hv.x, w[i4 * 4 + 0], a0);
            a1 = fmaf(hv.y, w[i4 * 4 + 1], a1);
            a2 = fmaf(hv.z, w[i4 * 4 + 2], a2);
            a3 = fmaf(hv.w, w[i4 * 4 + 3], a3);
        }
        float s = (a0 + a1) + (a2 + a3);
        s += __shfl_xor(s, 1);               // DPP quad-perm, no LDS round trip
        const float pre = xcur + bj + s;
        // tanh(x) = 1 - 2/(exp(2x)+1), exp via v_exp_f32 (2^x), rcp via v_rcp_f32
        const float e = exp2f(pre * 2.8853900817779268f);
        const float hnew = 1.f - 2.f * __builtin_amdgcn_rcpf(e + 1.f);
        if (!half) {
            hb[cur ^ 1][j] = hnew;           // write next buffer (no WAR hazard)
            xp[(long)t * H_ + j] = hnew;     // h_seq output, overwrites consumed xp
        }
        __syncthreads();
        cur ^= 1;
    }
    if (!half) hlast[b * H_ + j] = hb[cur][j];
}

extern "C" void kernel_launch(void* const* d_in, const int* in_sizes, int n_in,
                              void* d_out, int out_size, void* d_ws, size_t ws_size,
                              hipStream_t stream)
{
    const float* x   = (const float*)d_in[0];
    const float* Wxh = (const float*)d_in[1];
    const float* bxh = (const float*)d_in[2];
    const float* Whh = (const float*)d_in[3];
    const float* bhh = (const float*)d_in[4];
    float* out   = (float*)d_out;
    float* hlast = out + (size_t)B_ * T_ * H_;

    xp_gemm<<<(B_ * T_) / 128, 256, 0, stream>>>(x, Wxh, bxh, out);
    rnn_scan<<<B_, 256, 0, stream>>>(Whh, bhh, out, hlast);
}